// Round 1
// baseline (51.934 us; speedup 1.0000x reference)
//
#include <hip/hip_runtime.h>

// Shapes fixed by setup_inputs(): B=8, C=256, H=128, W=128
#define B_ 8
#define C_ 256
#define H_ 128
#define W_ 128
#define N_TOTAL (B_ * C_ * H_ * W_)      // 33,554,432
#define N_VEC   (N_TOTAL / 4)            // float4 count
#define NB1     2048
#define NT1     256
#define NSAMP   64
#define NB2     (B_ * NSAMP)             // 512

// Kernel 1: grand dot product sum_{all} q*t, per-block partials (deterministic)
__global__ __launch_bounds__(NT1) void dot_partial_kernel(
    const float4* __restrict__ q, const float4* __restrict__ t,
    float* __restrict__ partial) {
    int tid = blockIdx.x * NT1 + threadIdx.x;
    int stride = gridDim.x * NT1;
    float acc = 0.0f;
    for (int i = tid; i < N_VEC; i += stride) {
        float4 a = q[i];
        float4 b = t[i];
        acc += a.x * b.x + a.y * b.y + a.z * b.z + a.w * b.w;
    }
    // wave (64-lane) butterfly reduce
    #pragma unroll
    for (int off = 32; off > 0; off >>= 1) acc += __shfl_down(acc, off, 64);
    __shared__ float s[NT1 / 64];
    int wid = threadIdx.x >> 6;
    int lane = threadIdx.x & 63;
    if (lane == 0) s[wid] = acc;
    __syncthreads();
    if (threadIdx.x == 0) {
        float blocksum = 0.0f;
        #pragma unroll
        for (int w = 0; w < NT1 / 64; ++w) blocksum += s[w];
        partial[blockIdx.x] = blocksum;
    }
}

// Kernel 2: sim[b,n] = relu( sum_w T[b, idx1[n], w] * T[7-b, idx2[n], w] )
// one 64-lane wave per (b,n); each lane handles 2 w's.
__global__ __launch_bounds__(64) void sim_kernel(
    const float* __restrict__ t, const int* __restrict__ idx1,
    const int* __restrict__ idx2, float* __restrict__ partial) {
    int blk = blockIdx.x;              // 0..511
    int b = blk >> 6;
    int n = blk & (NSAMP - 1);
    int i1 = idx1[n];
    int i2 = idx2[n];
    const float* p1 = t + ((size_t)b * (C_ * H_) + i1) * W_;
    const float* p2 = t + ((size_t)(B_ - 1 - b) * (C_ * H_) + i2) * W_;
    int lane = threadIdx.x;            // 0..63
    float acc = p1[lane] * p2[lane] + p1[lane + 64] * p2[lane + 64];
    #pragma unroll
    for (int off = 32; off > 0; off >>= 1) acc += __shfl_down(acc, off, 64);
    if (lane == 0) partial[blk] = fmaxf(acc, 0.0f);
}

// Kernel 3: combine partials -> scalar
__global__ __launch_bounds__(256) void finalize_kernel(
    const float* __restrict__ p1, const float* __restrict__ p2,
    float* __restrict__ out) {
    float a = 0.0f;
    for (int i = threadIdx.x; i < NB1; i += 256) a += p1[i];
    float b = 0.0f;
    for (int i = threadIdx.x; i < NB2; i += 256) b += p2[i];
    #pragma unroll
    for (int off = 32; off > 0; off >>= 1) {
        a += __shfl_down(a, off, 64);
        b += __shfl_down(b, off, 64);
    }
    __shared__ float sa[4], sb[4];
    int wid = threadIdx.x >> 6;
    int lane = threadIdx.x & 63;
    if (lane == 0) { sa[wid] = a; sb[wid] = b; }
    __syncthreads();
    if (threadIdx.x == 0) {
        float A = sa[0] + sa[1] + sa[2] + sa[3];
        float Bs = sb[0] + sb[1] + sb[2] + sb[3];
        // dist.mean() = 1 - A / (B*W*H);  sim term mean over B*NSAMP
        out[0] = 1.0f - A / (float)(B_ * H_ * W_) + Bs / (float)NB2;
    }
}

extern "C" void kernel_launch(void* const* d_in, const int* in_sizes, int n_in,
                              void* d_out, int out_size, void* d_ws, size_t ws_size,
                              hipStream_t stream) {
    const float* query  = (const float*)d_in[0];
    const float* target = (const float*)d_in[1];
    const int*   idx1   = (const int*)d_in[2];
    const int*   idx2   = (const int*)d_in[3];
    float* out = (float*)d_out;

    float* partial1 = (float*)d_ws;              // NB1 floats
    float* partial2 = partial1 + NB1;            // NB2 floats

    dot_partial_kernel<<<NB1, NT1, 0, stream>>>(
        (const float4*)query, (const float4*)target, partial1);
    sim_kernel<<<NB2, 64, 0, stream>>>(target, idx1, idx2, partial2);
    finalize_kernel<<<1, 256, 0, stream>>>(partial1, partial2, out);
}